// Round 3
// baseline (103.052 us; speedup 1.0000x reference)
//
#include <hip/hip_runtime.h>
#include <hip/hip_bf16.h>

#define D 128
#define MARGIN 0.5f
#define NSPLIT 16      // j-splits; each wave: 64 rows x 512 cols
#define NCHUNK 32      // 512 cols / 16

typedef __attribute__((ext_vector_type(8))) short bf16x8;
typedef __attribute__((ext_vector_type(4))) float f32x4;

// ---------------- prep: bf16 convert + sq + init ----------------
__global__ void prep_kernel(const float* __restrict__ x,
                            float* __restrict__ sq,
                            unsigned* __restrict__ ap,
                            unsigned* __restrict__ an,
                            __hip_bfloat16* __restrict__ xb,
                            float* __restrict__ out, int n) {
    int tid = threadIdx.x;
    int row = blockIdx.x * 4 + (tid >> 6);
    int lane = tid & 63;
    const float2* xr = (const float2*)(x + (size_t)row * D);
    float2 v = xr[lane];
    __hip_bfloat162 b2;
    b2.x = __float2bfloat16(v.x);
    b2.y = __float2bfloat16(v.y);
    ((__hip_bfloat162*)(xb + (size_t)row * D))[lane] = b2;
    float s = v.x * v.x + v.y * v.y;
    #pragma unroll
    for (int o = 32; o > 0; o >>= 1) s += __shfl_xor(s, o, 64);
    if (lane == 0) {
        sq[row] = s;
        ap[row] = 0u;            // dist >= 0 -> 0 is a valid -inf for max
        an[row] = 0x7F800000u;   // +inf bits
    }
    if (blockIdx.x == 0 && tid == 0) *out = 0.0f;
}

// ---------------- gram: LDS-free, register-resident MFMA ----------------
// One wave = 64 rows x 512 cols. A-frags register-resident (loaded once from
// L2-hot global). B-frags streamed from global in 16-col chunks, register
// double-buffered (prefetch c+1 during compute c). No __syncthreads at all.
__launch_bounds__(256, 2)
__global__ void gram_kernel(const __hip_bfloat16* __restrict__ xb,
                            const float* __restrict__ sq,
                            const int* __restrict__ tgt,
                            unsigned* __restrict__ ap,
                            unsigned* __restrict__ an, int n) {
    const int tid  = threadIdx.x;
    const int wid  = tid >> 6;
    const int lane = tid & 63;
    const int quad = lane >> 4;
    const int l    = lane & 15;
    const int gw     = blockIdx.x * 4 + wid;   // 0..2047
    const int istrip = gw >> 4;                // 0..127
    const int jsplit = gw & 15;
    const int i0 = istrip * 64;
    const int j0 = jsplit * (16 * NCHUNK);     // 512-col window

    // A fragments: lane holds A[m = l][k = quad*8 + j] for each 16-row tile
    bf16x8 afrag[4][4];
    {
        const __hip_bfloat16* abase = xb + (size_t)(i0 + l) * D + quad * 8;
        #pragma unroll
        for (int mt = 0; mt < 4; ++mt)
            #pragma unroll
            for (int ks = 0; ks < 4; ++ks)
                afrag[mt][ks] = *(const bf16x8*)(abase + (size_t)mt * 16 * D + ks * 32);
    }

    // row labels: C/D row = quad*4 + reg within each 16-row tile
    int li[4][4];
    #pragma unroll
    for (int mt = 0; mt < 4; ++mt)
        #pragma unroll
        for (int reg = 0; reg < 4; ++reg)
            li[mt][reg] = tgt[i0 + mt * 16 + quad * 4 + reg];

    // running hardest pos/neg in t-space (t = sq_j - 2*dot); add sq_i at end
    float lap[16], lan[16];
    #pragma unroll
    for (int k = 0; k < 16; ++k) { lap[k] = -1e30f; lan[k] = 1e30f; }

    const __hip_bfloat16* bbase = xb + (size_t)(j0 + l) * D + quad * 8;

    bf16x8 bf[2][4];
    float  sj[2];
    int    tj[2];

    #define LOADB(buf, c)                                                   \
        do {                                                                \
            const __hip_bfloat16* p_ = bbase + (size_t)(c) * 16 * D;        \
            bf[buf][0] = *(const bf16x8*)(p_);                              \
            bf[buf][1] = *(const bf16x8*)(p_ + 32);                         \
            bf[buf][2] = *(const bf16x8*)(p_ + 64);                         \
            bf[buf][3] = *(const bf16x8*)(p_ + 96);                         \
            sj[buf] = sq[j0 + (c) * 16 + l];                                \
            tj[buf] = tgt[j0 + (c) * 16 + l];                               \
        } while (0)

    #define COMPUTE(buf)                                                    \
        do {                                                                \
            f32x4 acc[4];                                                   \
            _Pragma("unroll")                                               \
            for (int mt = 0; mt < 4; ++mt) acc[mt] = (f32x4){0.f,0.f,0.f,0.f}; \
            _Pragma("unroll")                                               \
            for (int ks = 0; ks < 4; ++ks)                                  \
                _Pragma("unroll")                                           \
                for (int mt = 0; mt < 4; ++mt)                              \
                    acc[mt] = __builtin_amdgcn_mfma_f32_16x16x32_bf16(      \
                        afrag[mt][ks], bf[buf][ks], acc[mt], 0, 0, 0);      \
            float sjc = sj[buf]; int tjc = tj[buf];                         \
            _Pragma("unroll")                                               \
            for (int mt = 0; mt < 4; ++mt)                                  \
                _Pragma("unroll")                                           \
                for (int reg = 0; reg < 4; ++reg) {                         \
                    float t = fmaf(-2.0f, acc[mt][reg], sjc);               \
                    bool same = (li[mt][reg] == tjc);                       \
                    lap[mt*4+reg] = fmaxf(lap[mt*4+reg], same ? t : -1e30f);\
                    lan[mt*4+reg] = fminf(lan[mt*4+reg], same ? 1e30f : t); \
                }                                                           \
        } while (0)

    LOADB(0, 0);
    for (int c = 0; c < NCHUNK; c += 2) {
        LOADB(1, c + 1);
        COMPUTE(0);
        if (c < NCHUNK - 2) LOADB(0, c + 2);
        COMPUTE(1);
    }
    #undef LOADB
    #undef COMPUTE

    // reduce across the 16 column-lanes (xor<16 stays within quad group)
    #pragma unroll
    for (int mt = 0; mt < 4; ++mt)
        #pragma unroll
        for (int reg = 0; reg < 4; ++reg) {
            float p = lap[mt*4+reg], q = lan[mt*4+reg];
            #pragma unroll
            for (int o = 1; o < 16; o <<= 1) {
                p = fmaxf(p, __shfl_xor(p, o, 64));
                q = fminf(q, __shfl_xor(q, o, 64));
            }
            if (l == mt * 4 + reg) {   // one writer lane per quad
                int gi = i0 + mt * 16 + quad * 4 + reg;
                float s = sq[gi];
                atomicMax(&ap[gi], __float_as_uint(fmaxf(s + p, 0.0f)));
                atomicMin(&an[gi], __float_as_uint(fmaxf(s + q, 0.0f)));
            }
        }
}

// ---------------- final: sum relu(ap - an + margin) ----------------
__global__ void final_kernel(const unsigned* __restrict__ ap,
                             const unsigned* __restrict__ an,
                             float* __restrict__ out, int n) {
    int i = blockIdx.x * blockDim.x + threadIdx.x;
    float v = 0.f;
    if (i < n) {
        float p = __uint_as_float(ap[i]);
        float q = __uint_as_float(an[i]);
        v = fmaxf(p - q + MARGIN, 0.0f);
    }
    #pragma unroll
    for (int o = 32; o > 0; o >>= 1) v += __shfl_xor(v, o, 64);
    __shared__ float ws[4];
    int lane = threadIdx.x & 63, w = threadIdx.x >> 6;
    if (lane == 0) ws[w] = v;
    __syncthreads();
    if (threadIdx.x == 0) atomicAdd(out, ws[0] + ws[1] + ws[2] + ws[3]);
}

extern "C" void kernel_launch(void* const* d_in, const int* in_sizes, int n_in,
                              void* d_out, int out_size, void* d_ws, size_t ws_size,
                              hipStream_t stream) {
    const float* x   = (const float*)d_in[0];
    const int*   tgt = (const int*)d_in[1];
    float* out = (float*)d_out;
    const int n = in_sizes[1];              // 8192

    float*          sq = (float*)d_ws;
    unsigned*       ap = (unsigned*)((char*)d_ws + (size_t)n * 4);
    unsigned*       an = ap + n;
    __hip_bfloat16* xb = (__hip_bfloat16*)((char*)d_ws + (size_t)n * 12);

    prep_kernel<<<n / 4, 256, 0, stream>>>(x, sq, ap, an, xb, out, n);
    gram_kernel<<<(n / 64) * NSPLIT / 4, 256, 0, stream>>>(xb, sq, tgt, ap, an, n);
    final_kernel<<<n / 256, 256, 0, stream>>>(ap, an, out, n);
}